// Round 1
// baseline (1157.980 us; speedup 1.0000x reference)
//
#include <hip/hip_runtime.h>
#include <math.h>

#define NN 4096
#define DD 512
#define INV_TAU 5.0f
#define EPSV 1e-15f

__device__ __forceinline__ float wave_sum(float v) {
#pragma unroll
  for (int o = 32; o > 0; o >>= 1) v += __shfl_down(v, o, 64);
  return v;
}

// ---------------- NT GEMM: C[i,j] = act(sum_k A[i,k]*B[j,k] + bias[j]) --------
// A:[M,K] row-major, B:[Nc,K] row-major. ACT: 0 none, 1 prelu(alpha_p[0])
template <int ACT>
__global__ __launch_bounds__(256) void gemm_nt(
    const float* __restrict__ A, const float* __restrict__ B,
    const float* __restrict__ bias, const float* __restrict__ alpha_p,
    float* __restrict__ C, int M, int Nc, int K) {
  __shared__ __align__(16) float As[32 * 68];
  __shared__ __align__(16) float Bs[32 * 68];
  const int tx = threadIdx.x & 15;
  const int ty = threadIdx.x >> 4;
  const int i0 = blockIdx.y * 64;
  const int j0 = blockIdx.x * 64;
  float acc[4][4] = {};
  for (int k0 = 0; k0 < K; k0 += 32) {
#pragma unroll
    for (int pass = 0; pass < 2; ++pass) {
      const int r = (threadIdx.x >> 3) + pass * 32;
      const int c4 = (threadIdx.x & 7) * 4;
      float4 av = *(const float4*)&A[(size_t)(i0 + r) * K + k0 + c4];
      float4 bv = *(const float4*)&B[(size_t)(j0 + r) * K + k0 + c4];
      As[(c4 + 0) * 68 + r] = av.x; As[(c4 + 1) * 68 + r] = av.y;
      As[(c4 + 2) * 68 + r] = av.z; As[(c4 + 3) * 68 + r] = av.w;
      Bs[(c4 + 0) * 68 + r] = bv.x; Bs[(c4 + 1) * 68 + r] = bv.y;
      Bs[(c4 + 2) * 68 + r] = bv.z; Bs[(c4 + 3) * 68 + r] = bv.w;
    }
    __syncthreads();
#pragma unroll 8
    for (int kk = 0; kk < 32; ++kk) {
      float4 a = *(const float4*)&As[kk * 68 + ty * 4];
      float4 b = *(const float4*)&Bs[kk * 68 + tx * 4];
      float ar[4] = {a.x, a.y, a.z, a.w};
      float br[4] = {b.x, b.y, b.z, b.w};
#pragma unroll
      for (int di = 0; di < 4; ++di)
#pragma unroll
        for (int dj = 0; dj < 4; ++dj)
          acc[di][dj] = fmaf(ar[di], br[dj], acc[di][dj]);
    }
    __syncthreads();
  }
  const float al = (ACT == 1) ? alpha_p[0] : 0.f;
#pragma unroll
  for (int di = 0; di < 4; ++di) {
    const int i = i0 + ty * 4 + di;
    float v[4];
#pragma unroll
    for (int dj = 0; dj < 4; ++dj) {
      const int j = j0 + tx * 4 + dj;
      float x = acc[di][dj] + bias[j];
      if (ACT == 1) x = (x >= 0.f) ? x : al * x;
      v[dj] = x;
    }
    float4 o = make_float4(v[0], v[1], v[2], v[3]);
    *(float4*)&C[(size_t)i * Nc + j0 + tx * 4] = o;
  }
}

// ---------------- row-wise L2 normalize in place (one block per row) ---------
__global__ __launch_bounds__(256) void rownorm(float* __restrict__ h) {
  const int row = blockIdx.x;
  const int t = threadIdx.x;
  const size_t base = (size_t)row * DD;
  float v0 = h[base + t];
  float v1 = h[base + 256 + t];
  float s = v0 * v0 + v1 * v1;
  s = wave_sum(s);
  __shared__ float wsum[4];
  const int lane = t & 63, wid = t >> 6;
  if (lane == 0) wsum[wid] = s;
  __syncthreads();
  if (t == 0) {
    float tot = wsum[0] + wsum[1] + wsum[2] + wsum[3];
    wsum[0] = 1.f / fmaxf(sqrtf(tot), 1e-12f);
  }
  __syncthreads();
  const float inv = wsum[0];
  h[base + t] = v0 * inv;
  h[base + 256 + t] = v1 * inv;
}

// ------------- fused similarity: 3 GEMM tiles + exp + masked reductions ------
// zb layout: r11, r11m, r12, r12m, r22, r22mT, c12, c12m (each NN floats)
__global__ __launch_bounds__(256) void sim_fused(
    const float* __restrict__ na, const float* __restrict__ nb,
    const int* __restrict__ mask, float* __restrict__ zb) {
  __shared__ __align__(16) float smem[4 * 32 * 68];
  __shared__ float sred[8][64];
  float* Ai = smem;
  float* Aj = smem + 32 * 68;
  float* Bi = smem + 2 * 32 * 68;
  float* Bj = smem + 3 * 32 * 68;
  const int tx = threadIdx.x & 15;
  const int ty = threadIdx.x >> 4;
  const int i0 = blockIdx.y * 64;
  const int j0 = blockIdx.x * 64;
  float a11[4][4] = {}, a12[4][4] = {}, a22[4][4] = {};
  for (int k0 = 0; k0 < DD; k0 += 32) {
#pragma unroll
    for (int pass = 0; pass < 2; ++pass) {
      const int r = (threadIdx.x >> 3) + pass * 32;
      const int c4 = (threadIdx.x & 7) * 4;
      const size_t oi = (size_t)(i0 + r) * DD + k0 + c4;
      const size_t oj = (size_t)(j0 + r) * DD + k0 + c4;
      float4 va = *(const float4*)&na[oi];
      float4 vb = *(const float4*)&na[oj];
      float4 vc = *(const float4*)&nb[oi];
      float4 vd = *(const float4*)&nb[oj];
      Ai[(c4 + 0) * 68 + r] = va.x; Ai[(c4 + 1) * 68 + r] = va.y;
      Ai[(c4 + 2) * 68 + r] = va.z; Ai[(c4 + 3) * 68 + r] = va.w;
      Aj[(c4 + 0) * 68 + r] = vb.x; Aj[(c4 + 1) * 68 + r] = vb.y;
      Aj[(c4 + 2) * 68 + r] = vb.z; Aj[(c4 + 3) * 68 + r] = vb.w;
      Bi[(c4 + 0) * 68 + r] = vc.x; Bi[(c4 + 1) * 68 + r] = vc.y;
      Bi[(c4 + 2) * 68 + r] = vc.z; Bi[(c4 + 3) * 68 + r] = vc.w;
      Bj[(c4 + 0) * 68 + r] = vd.x; Bj[(c4 + 1) * 68 + r] = vd.y;
      Bj[(c4 + 2) * 68 + r] = vd.z; Bj[(c4 + 3) * 68 + r] = vd.w;
    }
    __syncthreads();
#pragma unroll 8
    for (int kk = 0; kk < 32; ++kk) {
      float4 fai = *(const float4*)(Ai + kk * 68 + ty * 4);
      float4 faj = *(const float4*)(Aj + kk * 68 + tx * 4);
      float4 fbi = *(const float4*)(Bi + kk * 68 + ty * 4);
      float4 fbj = *(const float4*)(Bj + kk * 68 + tx * 4);
      float ai[4] = {fai.x, fai.y, fai.z, fai.w};
      float aj[4] = {faj.x, faj.y, faj.z, faj.w};
      float bi[4] = {fbi.x, fbi.y, fbi.z, fbi.w};
      float bj[4] = {fbj.x, fbj.y, fbj.z, fbj.w};
#pragma unroll
      for (int di = 0; di < 4; ++di)
#pragma unroll
        for (int dj = 0; dj < 4; ++dj) {
          a11[di][dj] = fmaf(ai[di], aj[dj], a11[di][dj]);
          a12[di][dj] = fmaf(ai[di], bj[dj], a12[di][dj]);
          a22[di][dj] = fmaf(bi[di], bj[dj], a22[di][dj]);
        }
    }
    __syncthreads();
  }
  // stage mask tiles into (now free) smem; zero reduction buffers
  int* mij = (int*)smem;          // [64][64]  m[i,j] tile
  int* mji = (int*)smem + 4096;   // [64][65]  m[j,i] tile (padded)
#pragma unroll
  for (int pass = 0; pass < 4; ++pass) {
    const int idx = threadIdx.x + pass * 256;
    const int r = idx >> 4;
    const int c4 = (idx & 15) * 4;
    int4 v = *(const int4*)&mask[(size_t)(i0 + r) * NN + j0 + c4];
    *(int4*)&mij[r * 64 + c4] = v;
    int4 w = *(const int4*)&mask[(size_t)(j0 + r) * NN + i0 + c4];
    mji[r * 65 + c4 + 0] = w.x;
    mji[r * 65 + c4 + 1] = w.y;
    mji[r * 65 + c4 + 2] = w.z;
    mji[r * 65 + c4 + 3] = w.w;
  }
  for (int t = threadIdx.x; t < 512; t += 256) ((float*)sred)[t] = 0.f;
  __syncthreads();
  float pr11[4] = {}, pr11m[4] = {}, pr12[4] = {}, pr12m[4] = {};
  float pr22[4] = {}, pr22m[4] = {}, pc12[4] = {}, pc12m[4] = {};
#pragma unroll
  for (int di = 0; di < 4; ++di)
#pragma unroll
    for (int dj = 0; dj < 4; ++dj) {
      const float e11 = __expf(a11[di][dj] * INV_TAU);
      const float e12 = __expf(a12[di][dj] * INV_TAU);
      const float e22 = __expf(a22[di][dj] * INV_TAU);
      const float mf = (float)mij[(ty * 4 + di) * 64 + tx * 4 + dj];
      const float mtf = (float)mji[(tx * 4 + dj) * 65 + ty * 4 + di];
      pr11[di] += e11; pr11m[di] += e11 * mf;
      pr12[di] += e12; pr12m[di] += e12 * mf;
      pr22[di] += e22; pr22m[di] += e22 * mtf;
      pc12[dj] += e12; pc12m[dj] += e12 * mf;
    }
#pragma unroll
  for (int d = 0; d < 4; ++d) {
    atomicAdd(&sred[0][ty * 4 + d], pr11[d]);
    atomicAdd(&sred[1][ty * 4 + d], pr11m[d]);
    atomicAdd(&sred[2][ty * 4 + d], pr12[d]);
    atomicAdd(&sred[3][ty * 4 + d], pr12m[d]);
    atomicAdd(&sred[4][ty * 4 + d], pr22[d]);
    atomicAdd(&sred[5][ty * 4 + d], pr22m[d]);
    atomicAdd(&sred[6][tx * 4 + d], pc12[d]);
    atomicAdd(&sred[7][tx * 4 + d], pc12m[d]);
  }
  __syncthreads();
  if (threadIdx.x < 64) {
    const int t = threadIdx.x;
    atomicAdd(&zb[0 * NN + i0 + t], sred[0][t]);
    atomicAdd(&zb[1 * NN + i0 + t], sred[1][t]);
    atomicAdd(&zb[2 * NN + i0 + t], sred[2][t]);
    atomicAdd(&zb[3 * NN + i0 + t], sred[3][t]);
    atomicAdd(&zb[4 * NN + i0 + t], sred[4][t]);
    atomicAdd(&zb[5 * NN + i0 + t], sred[5][t]);
    atomicAdd(&zb[6 * NN + j0 + t], sred[6][t]);
    atomicAdd(&zb[7 * NN + j0 + t], sred[7][t]);
  }
}

// ---------------- local InfoNCE finalize -------------------------------------
__global__ __launch_bounds__(256) void local_fin(const float* __restrict__ zb,
                                                 float* __restrict__ scal) {
  const int i = blockIdx.x * 256 + threadIdx.x;
  const float r11 = zb[i], r11m = zb[NN + i];
  const float r12 = zb[2 * NN + i], r12m = zb[3 * NN + i];
  const float r22 = zb[4 * NN + i], r22m = zb[5 * NN + i];
  const float c12 = zb[6 * NN + i], c12m = zb[7 * NN + i];
  float l1 = -logf(r12m / (r11 + r12 - r11m));
  float l2 = -logf(c12m / (r22 + c12 - r22m));
  l1 = wave_sum(l1);
  l2 = wave_sum(l2);
  __shared__ float b1[4], b2[4];
  const int lane = threadIdx.x & 63, wid = threadIdx.x >> 6;
  if (lane == 0) { b1[wid] = l1; b2[wid] = l2; }
  __syncthreads();
  if (threadIdx.x == 0) {
    atomicAdd(&scal[0], b1[0] + b1[1] + b1[2] + b1[3]);
    atomicAdd(&scal[1], b2[0] + b2[1] + b2[2] + b2[3]);
  }
}

// ---------------- column means of z1, z2 (readouts) --------------------------
__global__ __launch_bounds__(256) void colmean(const float* __restrict__ z1,
                                               const float* __restrict__ z2,
                                               float* __restrict__ s1,
                                               float* __restrict__ s2) {
  const int c = blockIdx.x * 256 + threadIdx.x;
  const int r0 = blockIdx.y * 256;
  float a = 0.f, b = 0.f;
  for (int r = r0; r < r0 + 256; ++r) {
    a += z1[(size_t)r * DD + c];
    b += z2[(size_t)r * DD + c];
  }
  atomicAdd(&s1[c], a * (1.f / NN));
  atomicAdd(&s2[c], b * (1.f / NN));
}

// ---------------- D x D matvec, one wave per output row ----------------------
__global__ __launch_bounds__(256) void matvec_wave(
    const float* __restrict__ M, const float* __restrict__ x,
    const float* __restrict__ bias, const float* __restrict__ alpha_p, int act,
    float* __restrict__ y) {
  const int wave = (blockIdx.x * 256 + threadIdx.x) >> 6;
  const int lane = threadIdx.x & 63;
  float acc = 0.f;
#pragma unroll
  for (int t = 0; t < 8; ++t)
    acc = fmaf(M[(size_t)wave * DD + lane + 64 * t], x[lane + 64 * t], acc);
  acc = wave_sum(acc);
  if (lane == 0) {
    if (bias) acc += bias[wave];
    if (act) { const float al = alpha_p[0]; acc = (acc >= 0.f) ? acc : al * acc; }
    y[wave] = acc;
  }
}

// ---------------- sigmoid/log reduce: pos with sp, neg with sn ---------------
__global__ __launch_bounds__(256) void logsig_k(
    const float* __restrict__ z, const float* __restrict__ sp,
    const float* __restrict__ sn, float* __restrict__ accP,
    float* __restrict__ accN) {
  const int lane = threadIdx.x & 63;
  const int wid = threadIdx.x >> 6;
  const int row = blockIdx.x * 4 + wid;
  float dp = 0.f, dn = 0.f;
#pragma unroll
  for (int t = 0; t < 8; ++t) {
    const float zv = z[(size_t)row * DD + lane + 64 * t];
    dp = fmaf(zv, sp[lane + 64 * t], dp);
    dn = fmaf(zv, sn[lane + 64 * t], dn);
  }
  dp = wave_sum(dp);
  dn = wave_sum(dn);
  __shared__ float bp[4], bn[4];
  if (lane == 0) {
    const float sg = 1.f / (1.f + __expf(-dp));
    bp[wid] = -logf(sg + EPSV);
    const float sg2 = 1.f / (1.f + __expf(-dn));
    bn[wid] = -logf(1.f - sg2 + EPSV);
  }
  __syncthreads();
  if (threadIdx.x == 0) {
    atomicAdd(accP, bp[0] + bp[1] + bp[2] + bp[3]);
    atomicAdd(accN, bn[0] + bn[1] + bn[2] + bn[3]);
  }
}

// ---------------- final combine ----------------------------------------------
__global__ void combine(const float* __restrict__ scal, float* __restrict__ out) {
  // scal: [sum1, sum2, P1, Ng1, P2, Ng2]
  const float local = 0.5f * (scal[0] + scal[1]) * (1.f / NN);
  const float glob = 0.25f * (scal[2] + scal[3] + scal[4] + scal[5]) * (1.f / NN);
  out[0] = 0.5f * local + 0.5f * glob;
}

extern "C" void kernel_launch(void* const* d_in, const int* in_sizes, int n_in,
                              void* d_out, int out_size, void* d_ws,
                              size_t ws_size, hipStream_t stream) {
  const float* z1 = (const float*)d_in[0];
  const float* z2 = (const float*)d_in[1];
  const float* lw1 = (const float*)d_in[2];
  const float* lb1 = (const float*)d_in[3];
  const float* la = (const float*)d_in[4];
  const float* lw2 = (const float*)d_in[5];
  const float* lb2 = (const float*)d_in[6];
  const float* gw1 = (const float*)d_in[7];
  const float* gb1 = (const float*)d_in[8];
  const float* ga = (const float*)d_in[9];
  const float* gw2 = (const float*)d_in[10];
  const float* gb2 = (const float*)d_in[11];
  const float* W = (const float*)d_in[12];
  const int* mask = (const int*)d_in[13];
  float* out = (float*)d_out;

  const size_t ND = (size_t)NN * DD;
  float* ws = (float*)d_ws;
  float* h1 = ws;            // N*D
  float* h2 = ws + ND;       // N*D
  float* p = ws + 2 * ND;    // N*D scratch
  float* zb = ws + 3 * ND;   // zeroed region: 8*NN + 1024 + 16 floats
  float* s1 = zb + 8 * NN;
  float* s2 = s1 + DD;
  float* scal = s2 + DD;     // [sum1,sum2,P1,Ng1,P2,Ng2]
  float* t1 = scal + 16;
  float* hg1 = t1 + DD;
  float* summ1 = hg1 + DD;
  float* t2 = summ1 + DD;
  float* hg2 = t2 + DD;
  float* summ2 = hg2 + DD;

  hipMemsetAsync(zb, 0, (8 * NN + 2 * DD + 16) * sizeof(float), stream);

  dim3 blk(256);
  dim3 gproj(DD / 64, NN / 64);  // (8, 64)

  // local projector: h1 = prelu(z1@lw1^T+lb1)@lw2^T+lb2 ; same for z2
  gemm_nt<1><<<gproj, blk, 0, stream>>>(z1, lw1, lb1, la, p, NN, DD, DD);
  gemm_nt<0><<<gproj, blk, 0, stream>>>(p, lw2, lb2, nullptr, h1, NN, DD, DD);
  gemm_nt<1><<<gproj, blk, 0, stream>>>(z2, lw1, lb1, la, p, NN, DD, DD);
  gemm_nt<0><<<gproj, blk, 0, stream>>>(p, lw2, lb2, nullptr, h2, NN, DD, DD);

  rownorm<<<NN, blk, 0, stream>>>(h1);  // h1 -> na (in place)
  rownorm<<<NN, blk, 0, stream>>>(h2);  // h2 -> nb

  sim_fused<<<dim3(NN / 64, NN / 64), blk, 0, stream>>>(h1, h2, mask, zb);
  local_fin<<<NN / 256, blk, 0, stream>>>(zb, scal);

  // global (DGI) part
  colmean<<<dim3(DD / 256, 16), blk, 0, stream>>>(z1, z2, s1, s2);
  matvec_wave<<<DD / 4, blk, 0, stream>>>(gw1, s1, gb1, ga, 1, t1);
  matvec_wave<<<DD / 4, blk, 0, stream>>>(gw2, t1, gb2, nullptr, 0, hg1);
  matvec_wave<<<DD / 4, blk, 0, stream>>>(W, hg1, nullptr, nullptr, 0, summ1);
  matvec_wave<<<DD / 4, blk, 0, stream>>>(gw1, s2, gb1, ga, 1, t2);
  matvec_wave<<<DD / 4, blk, 0, stream>>>(gw2, t2, gb2, nullptr, 0, hg2);
  matvec_wave<<<DD / 4, blk, 0, stream>>>(W, hg2, nullptr, nullptr, 0, summ2);

  // gloss(z1,z2): pos = z1@summ1 -> P1(scal[2]), neg = z2@summ1 -> Ng1(scal[3])
  // gloss(z2,z1): pos = z2@summ2 -> P2(scal[4]), neg = z1@summ2 -> Ng2(scal[5])
  logsig_k<<<NN / 4, blk, 0, stream>>>(z1, summ1, summ2, &scal[2], &scal[5]);
  logsig_k<<<NN / 4, blk, 0, stream>>>(z2, summ2, summ1, &scal[4], &scal[3]);

  combine<<<1, 1, 0, stream>>>(scal, out);
}

// Round 2
// 358.806 us; speedup vs baseline: 3.2273x; 3.2273x over previous
//
#include <hip/hip_runtime.h>
#include <math.h>

#define NN 4096
#define DD 512
#define INV_TAU 5.0f
#define EPSV 1e-15f

typedef unsigned short u16;
typedef __attribute__((ext_vector_type(8))) short short8;
typedef __attribute__((ext_vector_type(4))) float f32x4;

__device__ __forceinline__ void gld16(const void* g, void* l) {
  __builtin_amdgcn_global_load_lds(
      (const __attribute__((address_space(1))) unsigned int*)g,
      (__attribute__((address_space(3))) unsigned int*)l, 16, 0, 0);
}

__device__ __forceinline__ float bf2f(u16 u) {
  return __uint_as_float(((unsigned)u) << 16);
}
__device__ __forceinline__ u16 f2bf(float x) {  // RNE
  unsigned u = __float_as_uint(x);
  u += 0x7fff + ((u >> 16) & 1);
  return (u16)(u >> 16);
}

__device__ __forceinline__ float wave_sum(float v) {
#pragma unroll
  for (int o = 32; o > 0; o >>= 1) v += __shfl_down(v, o, 64);
  return v;
}

// ---------------- fp32 -> bf16 convert (n divisible by 1024) -----------------
__global__ __launch_bounds__(256) void tobf16(const float* __restrict__ s,
                                              u16* __restrict__ d, int n4) {
  const int i = blockIdx.x * 256 + threadIdx.x;
  if (i >= n4) return;
  float4 v = *(const float4*)&s[(size_t)i * 4];
  unsigned long long pk = (unsigned long long)f2bf(v.x) |
                          ((unsigned long long)f2bf(v.y) << 16) |
                          ((unsigned long long)f2bf(v.z) << 32) |
                          ((unsigned long long)f2bf(v.w) << 48);
  *(unsigned long long*)&d[(size_t)i * 4] = pk;
}

// ------------- MFMA NT GEMM: out[i,j] = act(sum_k A[i,k]B[j,k] + bias[j]) ----
// A:[4096,512] bf16, B:[512,512] bf16. tile 128x64, 256 thr (4 waves).
template <int ACT, int OUTBF>
__global__ __launch_bounds__(256) void gemm_mfma(
    const u16* __restrict__ A, const u16* __restrict__ B,
    const float* __restrict__ bias, const float* __restrict__ alpha_p,
    void* __restrict__ outv) {
  __shared__ u16 sA[128 * 32];
  __shared__ u16 sB[64 * 32];
  const int tid = threadIdx.x;
  const int w = tid >> 6, lane = tid & 63;
  const int rq = lane >> 2, cq = (lane & 3) * 8;
  const int quad = lane >> 4, m16 = lane & 15;
  const int i0 = blockIdx.y * 128, j0 = blockIdx.x * 64;
  f32x4 acc[2][4] = {};
  for (int k0 = 0; k0 < DD; k0 += 32) {
    __syncthreads();
    gld16(&A[(size_t)(i0 + w * 32 + rq) * DD + k0 + cq], &sA[(w * 32) * 32]);
    gld16(&A[(size_t)(i0 + w * 32 + 16 + rq) * DD + k0 + cq],
          &sA[(w * 32 + 16) * 32]);
    gld16(&B[(size_t)(j0 + w * 16 + rq) * DD + k0 + cq], &sB[(w * 16) * 32]);
    __syncthreads();
    short8 a0 = *(const short8*)&sA[(w * 32 + m16) * 32 + quad * 8];
    short8 a1 = *(const short8*)&sA[(w * 32 + 16 + m16) * 32 + quad * 8];
#pragma unroll
    for (int c = 0; c < 4; ++c) {
      short8 b = *(const short8*)&sB[(c * 16 + m16) * 32 + quad * 8];
      acc[0][c] = __builtin_amdgcn_mfma_f32_16x16x32_bf16(a0, b, acc[0][c], 0, 0, 0);
      acc[1][c] = __builtin_amdgcn_mfma_f32_16x16x32_bf16(a1, b, acc[1][c], 0, 0, 0);
    }
  }
  const float al = ACT ? alpha_p[0] : 0.f;
#pragma unroll
  for (int t = 0; t < 2; ++t)
#pragma unroll
    for (int c = 0; c < 4; ++c)
#pragma unroll
      for (int r = 0; r < 4; ++r) {
        const int row = i0 + w * 32 + t * 16 + quad * 4 + r;
        const int col = j0 + c * 16 + m16;
        float x = acc[t][c][r] + bias[col];
        if (ACT) x = (x >= 0.f) ? x : al * x;
        if (OUTBF)
          ((u16*)outv)[(size_t)row * DD + col] = f2bf(x);
        else
          ((float*)outv)[(size_t)row * DD + col] = x;
      }
}

// ---------------- row-wise L2 normalize: bf16 in -> bf16 out -----------------
__global__ __launch_bounds__(256) void rownorm_bf16(const u16* __restrict__ h,
                                                    u16* __restrict__ o) {
  const int row = blockIdx.x;
  const int t = threadIdx.x;
  const size_t base = (size_t)row * DD;
  float v0 = bf2f(h[base + t]);
  float v1 = bf2f(h[base + 256 + t]);
  float s = v0 * v0 + v1 * v1;
  s = wave_sum(s);
  __shared__ float wsum[4];
  const int lane = t & 63, wid = t >> 6;
  if (lane == 0) wsum[wid] = s;
  __syncthreads();
  if (t == 0) {
    float tot = wsum[0] + wsum[1] + wsum[2] + wsum[3];
    wsum[0] = 1.f / fmaxf(sqrtf(tot), 1e-12f);
  }
  __syncthreads();
  const float inv = wsum[0];
  o[base + t] = f2bf(v0 * inv);
  o[base + 256 + t] = f2bf(v1 * inv);
}

// ------------- fused similarity (MFMA): 3 products + exp + masked sums -------
// tile 128(i) x 64(j); zb: [r11, r11m, r12, r12m, c12, c12m, c22, c22m] x NN.
// S22 symmetry: r22m[i] == column-sum of e22*m[i,j]; r22[i] == column-sum e22.
__global__ __launch_bounds__(256) void sim_mfma(
    const u16* __restrict__ na, const u16* __restrict__ nb,
    const int* __restrict__ mask, float* __restrict__ zb) {
  __shared__ u16 sAi[128 * 32], sBi[128 * 32];
  __shared__ u16 sAj[64 * 32], sBj[64 * 32];
  __shared__ unsigned char smask[128 * 64];
  __shared__ float rred[4][128];
  __shared__ float cred[4][64];
  const int tid = threadIdx.x;
  const int w = tid >> 6, lane = tid & 63;
  const int rq = lane >> 2, cq = (lane & 3) * 8;
  const int quad = lane >> 4, m16 = lane & 15;
  const int i0 = blockIdx.y * 128, j0 = blockIdx.x * 64;
  f32x4 a11[2][4] = {}, a12[2][4] = {}, a22[2][4] = {};
  const int half = w & 1;
  const u16* src = (w < 2) ? na : nb;
  u16* rowpan = (w < 2) ? sAi : sBi;
  u16* colpan = (w < 2) ? sAj : sBj;
  for (int k0 = 0; k0 < DD; k0 += 32) {
    __syncthreads();
#pragma unroll
    for (int rr = 0; rr < 64; rr += 16)
      gld16(&src[(size_t)(i0 + half * 64 + rr + rq) * DD + k0 + cq],
            &rowpan[(half * 64 + rr) * 32]);
#pragma unroll
    for (int rr = 0; rr < 32; rr += 16)
      gld16(&src[(size_t)(j0 + half * 32 + rr + rq) * DD + k0 + cq],
            &colpan[(half * 32 + rr) * 32]);
    __syncthreads();
    short8 ai0 = *(const short8*)&sAi[(w * 32 + m16) * 32 + quad * 8];
    short8 ai1 = *(const short8*)&sAi[(w * 32 + 16 + m16) * 32 + quad * 8];
    short8 bi0 = *(const short8*)&sBi[(w * 32 + m16) * 32 + quad * 8];
    short8 bi1 = *(const short8*)&sBi[(w * 32 + 16 + m16) * 32 + quad * 8];
#pragma unroll
    for (int c = 0; c < 4; ++c) {
      short8 aj = *(const short8*)&sAj[(c * 16 + m16) * 32 + quad * 8];
      short8 bj = *(const short8*)&sBj[(c * 16 + m16) * 32 + quad * 8];
      a11[0][c] = __builtin_amdgcn_mfma_f32_16x16x32_bf16(ai0, aj, a11[0][c], 0, 0, 0);
      a11[1][c] = __builtin_amdgcn_mfma_f32_16x16x32_bf16(ai1, aj, a11[1][c], 0, 0, 0);
      a12[0][c] = __builtin_amdgcn_mfma_f32_16x16x32_bf16(ai0, bj, a12[0][c], 0, 0, 0);
      a12[1][c] = __builtin_amdgcn_mfma_f32_16x16x32_bf16(ai1, bj, a12[1][c], 0, 0, 0);
      a22[0][c] = __builtin_amdgcn_mfma_f32_16x16x32_bf16(bi0, bj, a22[0][c], 0, 0, 0);
      a22[1][c] = __builtin_amdgcn_mfma_f32_16x16x32_bf16(bi1, bj, a22[1][c], 0, 0, 0);
    }
  }
  // stage mask tile as bytes; zero col-reduction buffer
#pragma unroll
  for (int p = 0; p < 8; ++p) {
    const int idx = tid + p * 256;
    const int r = idx >> 4;
    const int c4 = (idx & 15) * 4;
    const int4 v = *(const int4*)&mask[(size_t)(i0 + r) * NN + j0 + c4];
    smask[r * 64 + c4 + 0] = (unsigned char)v.x;
    smask[r * 64 + c4 + 1] = (unsigned char)v.y;
    smask[r * 64 + c4 + 2] = (unsigned char)v.z;
    smask[r * 64 + c4 + 3] = (unsigned char)v.w;
  }
  ((float*)cred)[tid] = 0.f;
  __syncthreads();
  float r11s[2][4] = {}, r11m[2][4] = {}, r12s[2][4] = {}, r12m[2][4] = {};
  float c12s[4] = {}, c12m[4] = {}, c22s[4] = {}, c22m[4] = {};
#pragma unroll
  for (int t = 0; t < 2; ++t)
#pragma unroll
    for (int c = 0; c < 4; ++c)
#pragma unroll
      for (int r = 0; r < 4; ++r) {
        const float e11 = __expf(a11[t][c][r] * INV_TAU);
        const float e12 = __expf(a12[t][c][r] * INV_TAU);
        const float e22 = __expf(a22[t][c][r] * INV_TAU);
        const int il = w * 32 + t * 16 + quad * 4 + r;
        const int jl = c * 16 + m16;
        const float mv = (float)smask[il * 64 + jl];
        r11s[t][r] += e11;
        r11m[t][r] += e11 * mv;
        r12s[t][r] += e12;
        r12m[t][r] += e12 * mv;
        c12s[c] += e12;
        c12m[c] += e12 * mv;
        c22s[c] += e22;
        c22m[c] += e22 * mv;
      }
  // row reductions across the 16 cols held by the quad-group
#pragma unroll
  for (int t = 0; t < 2; ++t)
#pragma unroll
    for (int r = 0; r < 4; ++r) {
      float v0 = r11s[t][r], v1 = r11m[t][r], v2 = r12s[t][r], v3 = r12m[t][r];
#pragma unroll
      for (int o = 1; o < 16; o <<= 1) {
        v0 += __shfl_xor(v0, o, 64);
        v1 += __shfl_xor(v1, o, 64);
        v2 += __shfl_xor(v2, o, 64);
        v3 += __shfl_xor(v3, o, 64);
      }
      if (m16 == 0) {
        const int row = w * 32 + t * 16 + quad * 4 + r;
        rred[0][row] = v0;
        rred[1][row] = v1;
        rred[2][row] = v2;
        rred[3][row] = v3;
      }
    }
  // col reductions across the 4 quads
#pragma unroll
  for (int c = 0; c < 4; ++c) {
    float v0 = c12s[c], v1 = c12m[c], v2 = c22s[c], v3 = c22m[c];
    v0 += __shfl_xor(v0, 16, 64); v0 += __shfl_xor(v0, 32, 64);
    v1 += __shfl_xor(v1, 16, 64); v1 += __shfl_xor(v1, 32, 64);
    v2 += __shfl_xor(v2, 16, 64); v2 += __shfl_xor(v2, 32, 64);
    v3 += __shfl_xor(v3, 16, 64); v3 += __shfl_xor(v3, 32, 64);
    if (lane < 16) {
      atomicAdd(&cred[0][c * 16 + lane], v0);
      atomicAdd(&cred[1][c * 16 + lane], v1);
      atomicAdd(&cred[2][c * 16 + lane], v2);
      atomicAdd(&cred[3][c * 16 + lane], v3);
    }
  }
  __syncthreads();
  if (tid < 128) {
#pragma unroll
    for (int q = 0; q < 4; ++q) atomicAdd(&zb[q * NN + i0 + tid], rred[q][tid]);
  } else if (tid < 192) {
    const int t2 = tid - 128;
#pragma unroll
    for (int q = 0; q < 4; ++q)
      atomicAdd(&zb[(4 + q) * NN + j0 + t2], cred[q][t2]);
  }
}

// ---------------- local InfoNCE finalize -------------------------------------
__global__ __launch_bounds__(256) void local_fin(const float* __restrict__ zb,
                                                 float* __restrict__ scal) {
  const int i = blockIdx.x * 256 + threadIdx.x;
  const float r11 = zb[i], r11m = zb[NN + i];
  const float r12 = zb[2 * NN + i], r12m = zb[3 * NN + i];
  const float c12 = zb[4 * NN + i], c12m = zb[5 * NN + i];
  const float c22 = zb[6 * NN + i], c22m = zb[7 * NN + i];
  float l1 = -logf(r12m / (r11 + r12 - r11m));
  float l2 = -logf(c12m / (c22 + c12 - c22m));
  l1 = wave_sum(l1);
  l2 = wave_sum(l2);
  __shared__ float b1[4], b2[4];
  const int lane = threadIdx.x & 63, wid = threadIdx.x >> 6;
  if (lane == 0) { b1[wid] = l1; b2[wid] = l2; }
  __syncthreads();
  if (threadIdx.x == 0) {
    atomicAdd(&scal[0], b1[0] + b1[1] + b1[2] + b1[3]);
    atomicAdd(&scal[1], b2[0] + b2[1] + b2[2] + b2[3]);
  }
}

// ---------------- column means of z1, z2 (readouts) --------------------------
__global__ __launch_bounds__(256) void colmean(const float* __restrict__ z1,
                                               const float* __restrict__ z2,
                                               float* __restrict__ s1,
                                               float* __restrict__ s2) {
  const int c = blockIdx.x * 256 + threadIdx.x;
  const int r0 = blockIdx.y * 256;
  float a = 0.f, b = 0.f;
  for (int r = r0; r < r0 + 256; ++r) {
    a += z1[(size_t)r * DD + c];
    b += z2[(size_t)r * DD + c];
  }
  atomicAdd(&s1[c], a * (1.f / NN));
  atomicAdd(&s2[c], b * (1.f / NN));
}

// ---------------- D x D matvec, one wave per output row ----------------------
__global__ __launch_bounds__(256) void matvec_wave(
    const float* __restrict__ M, const float* __restrict__ x,
    const float* __restrict__ bias, const float* __restrict__ alpha_p, int act,
    float* __restrict__ y) {
  const int wave = (blockIdx.x * 256 + threadIdx.x) >> 6;
  const int lane = threadIdx.x & 63;
  float acc = 0.f;
#pragma unroll
  for (int t = 0; t < 8; ++t)
    acc = fmaf(M[(size_t)wave * DD + lane + 64 * t], x[lane + 64 * t], acc);
  acc = wave_sum(acc);
  if (lane == 0) {
    if (bias) acc += bias[wave];
    if (act) { const float al = alpha_p[0]; acc = (acc >= 0.f) ? acc : al * acc; }
    y[wave] = acc;
  }
}

// ---------------- sigmoid/log reduce: pos with sp, neg with sn ---------------
__global__ __launch_bounds__(256) void logsig_k(
    const float* __restrict__ z, const float* __restrict__ sp,
    const float* __restrict__ sn, float* __restrict__ accP,
    float* __restrict__ accN) {
  const int lane = threadIdx.x & 63;
  const int wid = threadIdx.x >> 6;
  const int row = blockIdx.x * 4 + wid;
  float dp = 0.f, dn = 0.f;
#pragma unroll
  for (int t = 0; t < 8; ++t) {
    const float zv = z[(size_t)row * DD + lane + 64 * t];
    dp = fmaf(zv, sp[lane + 64 * t], dp);
    dn = fmaf(zv, sn[lane + 64 * t], dn);
  }
  dp = wave_sum(dp);
  dn = wave_sum(dn);
  __shared__ float bp[4], bn[4];
  if (lane == 0) {
    const float sg = 1.f / (1.f + __expf(-dp));
    bp[wid] = -logf(sg + EPSV);
    const float sg2 = 1.f / (1.f + __expf(-dn));
    bn[wid] = -logf(1.f - sg2 + EPSV);
  }
  __syncthreads();
  if (threadIdx.x == 0) {
    atomicAdd(accP, bp[0] + bp[1] + bp[2] + bp[3]);
    atomicAdd(accN, bn[0] + bn[1] + bn[2] + bn[3]);
  }
}

// ---------------- final combine ----------------------------------------------
__global__ void combine(const float* __restrict__ scal, float* __restrict__ out) {
  const float local = 0.5f * (scal[0] + scal[1]) * (1.f / NN);
  const float glob = 0.25f * (scal[2] + scal[3] + scal[4] + scal[5]) * (1.f / NN);
  out[0] = 0.5f * local + 0.5f * glob;
}

extern "C" void kernel_launch(void* const* d_in, const int* in_sizes, int n_in,
                              void* d_out, int out_size, void* d_ws,
                              size_t ws_size, hipStream_t stream) {
  const float* z1 = (const float*)d_in[0];
  const float* z2 = (const float*)d_in[1];
  const float* lw1 = (const float*)d_in[2];
  const float* lb1 = (const float*)d_in[3];
  const float* la = (const float*)d_in[4];
  const float* lw2 = (const float*)d_in[5];
  const float* lb2 = (const float*)d_in[6];
  const float* gw1 = (const float*)d_in[7];
  const float* gb1 = (const float*)d_in[8];
  const float* ga = (const float*)d_in[9];
  const float* gw2 = (const float*)d_in[10];
  const float* gb2 = (const float*)d_in[11];
  const float* W = (const float*)d_in[12];
  const int* mask = (const int*)d_in[13];
  float* out = (float*)d_out;

  const size_t ND = (size_t)NN * DD;
  u16* W1b = (u16*)d_ws;           // 512*512 bf16
  u16* W2b = W1b + 512 * 512;
  u16* Ab = W2b + 512 * 512;       // N*D bf16 (z converted)
  u16* Pb = Ab + ND;               // N*D bf16 (prelu output)
  u16* Hb = Pb + ND;               // N*D bf16 (projector output)
  u16* NAb = Hb + ND;              // N*D bf16 (normalized h1)
  u16* NBb = NAb + ND;             // N*D bf16 (normalized h2)
  float* zbf = (float*)(NBb + ND); // 8*NN
  float* s1 = zbf + 8 * NN;
  float* s2 = s1 + DD;
  float* scal = s2 + DD;           // [sum1,sum2,P1,Ng1,P2,Ng2]
  float* t1 = scal + 16;
  float* hg1 = t1 + DD;
  float* summ1 = hg1 + DD;
  float* t2 = summ1 + DD;
  float* hg2 = t2 + DD;
  float* summ2 = hg2 + DD;

  hipMemsetAsync(zbf, 0, (8 * NN + 2 * DD + 16) * sizeof(float), stream);

  dim3 blk(256);
  const int nz4 = NN * DD / 4, nw4 = 512 * 512 / 4;
  tobf16<<<nw4 / 256, blk, 0, stream>>>(lw1, W1b, nw4);
  tobf16<<<nw4 / 256, blk, 0, stream>>>(lw2, W2b, nw4);

  dim3 gg(512 / 64, NN / 128);  // (8, 32)
  // phase 1: z1 -> na
  tobf16<<<nz4 / 256, blk, 0, stream>>>(z1, Ab, nz4);
  gemm_mfma<1, 1><<<gg, blk, 0, stream>>>(Ab, W1b, lb1, la, Pb);
  gemm_mfma<0, 1><<<gg, blk, 0, stream>>>(Pb, W2b, lb2, nullptr, Hb);
  rownorm_bf16<<<NN, blk, 0, stream>>>(Hb, NAb);
  // phase 2: z2 -> nb
  tobf16<<<nz4 / 256, blk, 0, stream>>>(z2, Ab, nz4);
  gemm_mfma<1, 1><<<gg, blk, 0, stream>>>(Ab, W1b, lb1, la, Pb);
  gemm_mfma<0, 1><<<gg, blk, 0, stream>>>(Pb, W2b, lb2, nullptr, Hb);
  rownorm_bf16<<<NN, blk, 0, stream>>>(Hb, NBb);

  sim_mfma<<<dim3(NN / 64, NN / 128), blk, 0, stream>>>(NAb, NBb, mask, zbf);
  local_fin<<<NN / 256, blk, 0, stream>>>(zbf, scal);

  // global (DGI) part — fp32, tiny
  colmean<<<dim3(DD / 256, 16), blk, 0, stream>>>(z1, z2, s1, s2);
  matvec_wave<<<DD / 4, blk, 0, stream>>>(gw1, s1, gb1, ga, 1, t1);
  matvec_wave<<<DD / 4, blk, 0, stream>>>(gw2, t1, gb2, nullptr, 0, hg1);
  matvec_wave<<<DD / 4, blk, 0, stream>>>(W, hg1, nullptr, nullptr, 0, summ1);
  matvec_wave<<<DD / 4, blk, 0, stream>>>(gw1, s2, gb1, ga, 1, t2);
  matvec_wave<<<DD / 4, blk, 0, stream>>>(gw2, t2, gb2, nullptr, 0, hg2);
  matvec_wave<<<DD / 4, blk, 0, stream>>>(W, hg2, nullptr, nullptr, 0, summ2);

  logsig_k<<<NN / 4, blk, 0, stream>>>(z1, summ1, summ2, &scal[2], &scal[5]);
  logsig_k<<<NN / 4, blk, 0, stream>>>(z2, summ2, summ1, &scal[4], &scal[3]);

  combine<<<1, 1, 0, stream>>>(scal, out);
}

// Round 3
// 309.051 us; speedup vs baseline: 3.7469x; 1.1610x over previous
//
#include <hip/hip_runtime.h>
#include <math.h>

#define NN 4096
#define DD 512
#define INV_TAU 5.0f
#define EPSV 1e-15f

typedef unsigned short u16;
typedef __attribute__((ext_vector_type(8))) short short8;
typedef __attribute__((ext_vector_type(4))) float f32x4;

__device__ __forceinline__ void gld16(const void* g, void* l) {
  __builtin_amdgcn_global_load_lds(
      (const __attribute__((address_space(1))) unsigned int*)g,
      (__attribute__((address_space(3))) unsigned int*)l, 16, 0, 0);
}

__device__ __forceinline__ float bf2f(u16 u) {
  return __uint_as_float(((unsigned)u) << 16);
}
__device__ __forceinline__ u16 f2bf(float x) {  // RNE
  unsigned u = __float_as_uint(x);
  u += 0x7fff + ((u >> 16) & 1);
  return (u16)(u >> 16);
}

__device__ __forceinline__ float wave_sum(float v) {
#pragma unroll
  for (int o = 32; o > 0; o >>= 1) v += __shfl_down(v, o, 64);
  return v;
}

// ---------------- fp32 -> bf16 convert, two sources -> contiguous dst --------
__global__ __launch_bounds__(256) void tobf16_2(const float* __restrict__ a,
                                                const float* __restrict__ b,
                                                u16* __restrict__ d,
                                                int n4each) {
  const int i = blockIdx.x * 256 + threadIdx.x;
  const float* s =
      (i < n4each) ? a + (size_t)i * 4 : b + (size_t)(i - n4each) * 4;
  float4 v = *(const float4*)s;
  unsigned long long pk = (unsigned long long)f2bf(v.x) |
                          ((unsigned long long)f2bf(v.y) << 16) |
                          ((unsigned long long)f2bf(v.z) << 32) |
                          ((unsigned long long)f2bf(v.w) << 48);
  *(unsigned long long*)&d[(size_t)i * 4] = pk;
}

// ------------- MFMA NT GEMM, pipelined: out = act(A@Bw^T + bias) -------------
// A:[2,4096,512] bf16 (batch z), Bw:[512,512] bf16. tile 128x128, 4 waves.
template <int ACT>
__global__ __launch_bounds__(256) void gemm_mfma(
    const u16* __restrict__ A, const u16* __restrict__ Bw,
    const float* __restrict__ bias, const float* __restrict__ alpha_p,
    u16* __restrict__ out) {
  __shared__ __align__(16) u16 sA[2][128 * 32], sB[2][128 * 32];
  const int tid = threadIdx.x, w = tid >> 6, lane = tid & 63;
  const int rq = lane >> 2, cq = (lane & 3) * 8;
  const int quad = lane >> 4, m16 = lane & 15;
  const int wi = w >> 1, wj = w & 1;
  const int i0 = blockIdx.y * 128, j0 = blockIdx.x * 128;
  const u16* Ab = A + (size_t)blockIdx.z * ((size_t)NN * DD);
  u16* ob = out + (size_t)blockIdx.z * ((size_t)NN * DD);
  // staging role: wave w stages panel p (0=A,1=B), rows rh..rh+63
  const int p = w >> 1, rh = (w & 1) * 64;
  const u16* gs = p ? Bw : Ab;
  const int grow0 = (p ? j0 : i0) + rh + rq;
  u16* lb0 = p ? &sB[0][rh * 32] : &sA[0][rh * 32];
  u16* lb1 = p ? &sB[1][rh * 32] : &sA[1][rh * 32];
#pragma unroll
  for (int rr = 0; rr < 64; rr += 16)
    gld16(&gs[(size_t)(grow0 + rr) * DD + cq], lb0 + rr * 32);
  f32x4 acc[4][4] = {};
  for (int kc = 0; kc < 16; ++kc) {
    __syncthreads();
    if (kc < 15) {  // prefetch next chunk into alternate buffer (async)
      const int kn = (kc + 1) * 32;
      u16* d = (kc & 1) ? lb0 : lb1;
#pragma unroll
      for (int rr = 0; rr < 64; rr += 16)
        gld16(&gs[(size_t)(grow0 + rr) * DD + kn + cq], d + rr * 32);
    }
    const u16* As = sA[kc & 1];
    const u16* Bs = sB[kc & 1];
    short8 ar[4], br[4];
#pragma unroll
    for (int s = 0; s < 4; ++s) {
      ar[s] = *(const short8*)&As[(wi * 64 + s * 16 + m16) * 32 + quad * 8];
      br[s] = *(const short8*)&Bs[(wj * 64 + s * 16 + m16) * 32 + quad * 8];
    }
#pragma unroll
    for (int si = 0; si < 4; ++si)
#pragma unroll
      for (int sj = 0; sj < 4; ++sj)
        acc[si][sj] = __builtin_amdgcn_mfma_f32_16x16x32_bf16(
            ar[si], br[sj], acc[si][sj], 0, 0, 0);
  }
  const float al = ACT ? alpha_p[0] : 0.f;
#pragma unroll
  for (int si = 0; si < 4; ++si)
#pragma unroll
    for (int sj = 0; sj < 4; ++sj) {
      const int col = j0 + wj * 64 + sj * 16 + m16;
      const float bv = bias[col];
#pragma unroll
      for (int r = 0; r < 4; ++r) {
        const int row = i0 + wi * 64 + si * 16 + quad * 4 + r;
        float x = acc[si][sj][r] + bv;
        if (ACT) x = (x >= 0.f) ? x : al * x;
        ob[(size_t)row * DD + col] = f2bf(x);
      }
    }
}

// ---------------- row-wise L2 normalize: bf16 in -> bf16 out -----------------
__global__ __launch_bounds__(256) void rownorm_bf16(const u16* __restrict__ h,
                                                    u16* __restrict__ o) {
  const int row = blockIdx.x;
  const int t = threadIdx.x;
  const size_t base = (size_t)row * DD;
  float v0 = bf2f(h[base + t]);
  float v1 = bf2f(h[base + 256 + t]);
  float s = v0 * v0 + v1 * v1;
  s = wave_sum(s);
  __shared__ float wsum[4];
  const int lane = t & 63, wid = t >> 6;
  if (lane == 0) wsum[wid] = s;
  __syncthreads();
  if (t == 0) {
    float tot = wsum[0] + wsum[1] + wsum[2] + wsum[3];
    wsum[0] = 1.f / fmaxf(sqrtf(tot), 1e-12f);
  }
  __syncthreads();
  const float inv = wsum[0];
  o[base + t] = f2bf(v0 * inv);
  o[base + 256 + t] = f2bf(v1 * inv);
}

// ------------- fused similarity (MFMA, pipelined): 3 products + exp + sums ---
// tile 128(i) x 128(j), 512 thr (8 waves: ig = w&3 i-group, jh = w>>2 j-half).
// zb: [r11, r11m, r12, r12m, c12, c12m, c22, c22m] x NN.
// S22 symmetry: its row stats come from column sums (r22 == c22 etc).
__global__ __launch_bounds__(512) void sim_mfma(
    const u16* __restrict__ na, const u16* __restrict__ nb,
    const int* __restrict__ mask, float* __restrict__ zb) {
  __shared__ __align__(16) u16 sP[2][4][128 * 32];  // 64 KiB exactly
  const int tid = threadIdx.x;
  const int w = tid >> 6, lane = tid & 63;
  const int rq = lane >> 2, cq = (lane & 3) * 8;
  const int quad = lane >> 4, m16 = lane & 15;
  const int ig = w & 3, jh = w >> 2;
  const int i0 = blockIdx.y * 128, j0 = blockIdx.x * 128;
  // staging role: wave w stages panel p, rows rh..rh+63 of that panel
  const int p = w >> 1, rh = (w & 1) * 64;
  const u16* gs = (p & 1) ? nb : na;     // panels: 0 na_i, 1 nb_i, 2 na_j, 3 nb_j
  const int grow0 = ((p < 2) ? i0 : j0) + rh + rq;
  u16* lb0 = &sP[0][p][rh * 32];
  u16* lb1 = &sP[1][p][rh * 32];
#pragma unroll
  for (int rr = 0; rr < 64; rr += 16)
    gld16(&gs[(size_t)(grow0 + rr) * DD + cq], lb0 + rr * 32);
  f32x4 a11[2][4] = {}, a12[2][4] = {}, a22[2][4] = {};
  for (int kc = 0; kc < 16; ++kc) {
    __syncthreads();
    if (kc < 15) {  // async prefetch into alternate buffer
      const int kn = (kc + 1) * 32;
      u16* d = (kc & 1) ? lb0 : lb1;
#pragma unroll
      for (int rr = 0; rr < 64; rr += 16)
        gld16(&gs[(size_t)(grow0 + rr) * DD + kn + cq], d + rr * 32);
    }
    const u16* Ai = sP[kc & 1][0];
    const u16* Bi = sP[kc & 1][1];
    const u16* Aj = sP[kc & 1][2];
    const u16* Bj = sP[kc & 1][3];
    short8 ai0 = *(const short8*)&Ai[(ig * 32 + m16) * 32 + quad * 8];
    short8 ai1 = *(const short8*)&Ai[(ig * 32 + 16 + m16) * 32 + quad * 8];
    short8 bi0 = *(const short8*)&Bi[(ig * 32 + m16) * 32 + quad * 8];
    short8 bi1 = *(const short8*)&Bi[(ig * 32 + 16 + m16) * 32 + quad * 8];
#pragma unroll
    for (int c = 0; c < 4; ++c) {
      short8 aj = *(const short8*)&Aj[(jh * 64 + c * 16 + m16) * 32 + quad * 8];
      short8 bj = *(const short8*)&Bj[(jh * 64 + c * 16 + m16) * 32 + quad * 8];
      a11[0][c] = __builtin_amdgcn_mfma_f32_16x16x32_bf16(ai0, aj, a11[0][c], 0, 0, 0);
      a11[1][c] = __builtin_amdgcn_mfma_f32_16x16x32_bf16(ai1, aj, a11[1][c], 0, 0, 0);
      a12[0][c] = __builtin_amdgcn_mfma_f32_16x16x32_bf16(ai0, bj, a12[0][c], 0, 0, 0);
      a12[1][c] = __builtin_amdgcn_mfma_f32_16x16x32_bf16(ai1, bj, a12[1][c], 0, 0, 0);
      a22[0][c] = __builtin_amdgcn_mfma_f32_16x16x32_bf16(bi0, bj, a22[0][c], 0, 0, 0);
      a22[1][c] = __builtin_amdgcn_mfma_f32_16x16x32_bf16(bi1, bj, a22[1][c], 0, 0, 0);
    }
  }
  // reductions overlay buffer 0 (free: last chunk reads buffer 1)
  float* rred = (float*)&sP[0][0][0];  // [4][128] row stats
  float* cred = rred + 512;            // [4][128] col stats
  rred[tid] = 0.f;
  rred[tid + 512] = 0.f;
  __syncthreads();
  float rs11[2][4] = {}, rm11[2][4] = {}, rs12[2][4] = {}, rm12[2][4] = {};
  float cs12[4] = {}, cm12[4] = {}, cs22[4] = {}, cm22[4] = {};
#pragma unroll
  for (int t = 0; t < 2; ++t)
#pragma unroll
    for (int c = 0; c < 4; ++c) {
      const int gj = j0 + jh * 64 + c * 16 + m16;
#pragma unroll
      for (int r = 0; r < 4; ++r) {
        const int gi = i0 + ig * 32 + t * 16 + quad * 4 + r;
        const float mv = (float)mask[(size_t)gi * NN + gj];
        const float e11 = __expf(a11[t][c][r] * INV_TAU);
        const float e12 = __expf(a12[t][c][r] * INV_TAU);
        const float e22 = __expf(a22[t][c][r] * INV_TAU);
        rs11[t][r] += e11;
        rm11[t][r] += e11 * mv;
        rs12[t][r] += e12;
        rm12[t][r] += e12 * mv;
        cs12[c] += e12;
        cm12[c] += e12 * mv;
        cs22[c] += e22;
        cm22[c] += e22 * mv;
      }
    }
#pragma unroll
  for (int t = 0; t < 2; ++t)
#pragma unroll
    for (int r = 0; r < 4; ++r) {
      float v0 = rs11[t][r], v1 = rm11[t][r], v2 = rs12[t][r], v3 = rm12[t][r];
#pragma unroll
      for (int o = 1; o < 16; o <<= 1) {
        v0 += __shfl_xor(v0, o, 64);
        v1 += __shfl_xor(v1, o, 64);
        v2 += __shfl_xor(v2, o, 64);
        v3 += __shfl_xor(v3, o, 64);
      }
      if (m16 == 0) {
        const int il = ig * 32 + t * 16 + quad * 4 + r;
        atomicAdd(&rred[0 * 128 + il], v0);
        atomicAdd(&rred[1 * 128 + il], v1);
        atomicAdd(&rred[2 * 128 + il], v2);
        atomicAdd(&rred[3 * 128 + il], v3);
      }
    }
#pragma unroll
  for (int c = 0; c < 4; ++c) {
    float v0 = cs12[c], v1 = cm12[c], v2 = cs22[c], v3 = cm22[c];
    v0 += __shfl_xor(v0, 16, 64); v0 += __shfl_xor(v0, 32, 64);
    v1 += __shfl_xor(v1, 16, 64); v1 += __shfl_xor(v1, 32, 64);
    v2 += __shfl_xor(v2, 16, 64); v2 += __shfl_xor(v2, 32, 64);
    v3 += __shfl_xor(v3, 16, 64); v3 += __shfl_xor(v3, 32, 64);
    if (lane < 16) {
      const int jl = jh * 64 + c * 16 + lane;
      atomicAdd(&cred[0 * 128 + jl], v0);
      atomicAdd(&cred[1 * 128 + jl], v1);
      atomicAdd(&cred[2 * 128 + jl], v2);
      atomicAdd(&cred[3 * 128 + jl], v3);
    }
  }
  __syncthreads();
  if (tid < 128) {
#pragma unroll
    for (int q = 0; q < 4; ++q)
      atomicAdd(&zb[q * NN + i0 + tid], rred[q * 128 + tid]);
  } else if (tid < 256) {
    const int jl = tid - 128;
#pragma unroll
    for (int q = 0; q < 4; ++q)
      atomicAdd(&zb[(4 + q) * NN + j0 + jl], cred[q * 128 + jl]);
  }
}

// ---------------- local InfoNCE finalize -------------------------------------
__global__ __launch_bounds__(256) void local_fin(const float* __restrict__ zb,
                                                 float* __restrict__ scal) {
  const int i = blockIdx.x * 256 + threadIdx.x;
  const float r11 = zb[i], r11m = zb[NN + i];
  const float r12 = zb[2 * NN + i], r12m = zb[3 * NN + i];
  const float c12 = zb[4 * NN + i], c12m = zb[5 * NN + i];
  const float c22 = zb[6 * NN + i], c22m = zb[7 * NN + i];
  float l1 = -logf(r12m / (r11 + r12 - r11m));
  float l2 = -logf(c12m / (c22 + c12 - c22m));
  l1 = wave_sum(l1);
  l2 = wave_sum(l2);
  __shared__ float b1[4], b2[4];
  const int lane = threadIdx.x & 63, wid = threadIdx.x >> 6;
  if (lane == 0) { b1[wid] = l1; b2[wid] = l2; }
  __syncthreads();
  if (threadIdx.x == 0) {
    atomicAdd(&scal[0], b1[0] + b1[1] + b1[2] + b1[3]);
    atomicAdd(&scal[1], b2[0] + b2[1] + b2[2] + b2[3]);
  }
}

// ---------------- column means of z1, z2 (readouts) --------------------------
__global__ __launch_bounds__(256) void colmean(const float* __restrict__ z1,
                                               const float* __restrict__ z2,
                                               float* __restrict__ s1,
                                               float* __restrict__ s2) {
  const int c = blockIdx.x * 256 + threadIdx.x;
  const int r0 = blockIdx.y * 64;
  float a = 0.f, b = 0.f;
  for (int r = r0; r < r0 + 64; ++r) {
    a += z1[(size_t)r * DD + c];
    b += z2[(size_t)r * DD + c];
  }
  atomicAdd(&s1[c], a * (1.f / NN));
  atomicAdd(&s2[c], b * (1.f / NN));
}

// ---------------- paired D x D matvec, one wave per output row ---------------
__global__ __launch_bounds__(256) void matvec2(
    const float* __restrict__ M, const float* __restrict__ x1,
    const float* __restrict__ x2, const float* __restrict__ bias,
    const float* __restrict__ alpha_p, int act, float* __restrict__ y1,
    float* __restrict__ y2) {
  const float* x = blockIdx.y ? x2 : x1;
  float* y = blockIdx.y ? y2 : y1;
  const int row = (blockIdx.x * 256 + threadIdx.x) >> 6;
  const int lane = threadIdx.x & 63;
  float acc = 0.f;
#pragma unroll
  for (int t = 0; t < 8; ++t)
    acc = fmaf(M[(size_t)row * DD + lane + 64 * t], x[lane + 64 * t], acc);
  acc = wave_sum(acc);
  if (lane == 0) {
    if (bias) acc += bias[row];
    if (act) { const float al = alpha_p[0]; acc = (acc >= 0.f) ? acc : al * acc; }
    y[row] = acc;
  }
}

// ---------------- paired sigmoid/log reduce ----------------------------------
__global__ __launch_bounds__(256) void logsig2(
    const float* __restrict__ z1, const float* __restrict__ z2,
    const float* __restrict__ sm1, const float* __restrict__ sm2,
    float* __restrict__ scal) {
  const int ch = blockIdx.y;
  const float* z = ch ? z2 : z1;
  const float* sp = ch ? sm2 : sm1;
  const float* sn = ch ? sm1 : sm2;
  float* accP = ch ? &scal[4] : &scal[2];
  float* accN = ch ? &scal[3] : &scal[5];
  const int lane = threadIdx.x & 63;
  const int wid = threadIdx.x >> 6;
  const int row = blockIdx.x * 4 + wid;
  float dp = 0.f, dn = 0.f;
#pragma unroll
  for (int t = 0; t < 8; ++t) {
    const float zv = z[(size_t)row * DD + lane + 64 * t];
    dp = fmaf(zv, sp[lane + 64 * t], dp);
    dn = fmaf(zv, sn[lane + 64 * t], dn);
  }
  dp = wave_sum(dp);
  dn = wave_sum(dn);
  __shared__ float bp[4], bn[4];
  if (lane == 0) {
    const float sg = 1.f / (1.f + __expf(-dp));
    bp[wid] = -logf(sg + EPSV);
    const float sg2 = 1.f / (1.f + __expf(-dn));
    bn[wid] = -logf(1.f - sg2 + EPSV);
  }
  __syncthreads();
  if (threadIdx.x == 0) {
    atomicAdd(accP, bp[0] + bp[1] + bp[2] + bp[3]);
    atomicAdd(accN, bn[0] + bn[1] + bn[2] + bn[3]);
  }
}

// ---------------- final combine ----------------------------------------------
__global__ void combine(const float* __restrict__ scal, float* __restrict__ out) {
  const float local = 0.5f * (scal[0] + scal[1]) * (1.f / NN);
  const float glob = 0.25f * (scal[2] + scal[3] + scal[4] + scal[5]) * (1.f / NN);
  out[0] = 0.5f * local + 0.5f * glob;
}

extern "C" void kernel_launch(void* const* d_in, const int* in_sizes, int n_in,
                              void* d_out, int out_size, void* d_ws,
                              size_t ws_size, hipStream_t stream) {
  const float* z1 = (const float*)d_in[0];
  const float* z2 = (const float*)d_in[1];
  const float* lw1 = (const float*)d_in[2];
  const float* lb1 = (const float*)d_in[3];
  const float* la = (const float*)d_in[4];
  const float* lw2 = (const float*)d_in[5];
  const float* lb2 = (const float*)d_in[6];
  const float* gw1 = (const float*)d_in[7];
  const float* gb1 = (const float*)d_in[8];
  const float* ga = (const float*)d_in[9];
  const float* gw2 = (const float*)d_in[10];
  const float* gb2 = (const float*)d_in[11];
  const float* W = (const float*)d_in[12];
  const int* mask = (const int*)d_in[13];
  float* out = (float*)d_out;

  const size_t ND = (size_t)NN * DD;
  u16* W1b = (u16*)d_ws;                 // [2][512*512] (W1b, W2b contiguous)
  u16* W2b = W1b + 512 * 512;
  u16* Ab = W1b + 2 * 512 * 512;         // [2][N*D] bf16
  u16* Bb = Ab + 2 * ND;                 // [2][N*D] bf16
  float* zbf = (float*)(Bb + 2 * ND);    // 8*NN
  float* s1 = zbf + 8 * NN;
  float* s2 = s1 + DD;
  float* scal = s2 + DD;                 // [sum1,sum2,P1,Ng1,P2,Ng2]
  float* t1 = scal + 16;
  float* hg1 = t1 + DD;
  float* summ1 = hg1 + DD;
  float* t2 = summ1 + DD;
  float* hg2 = t2 + DD;
  float* summ2 = hg2 + DD;

  hipMemsetAsync(zbf, 0, (8 * NN + 2 * DD + 16) * sizeof(float), stream);

  dim3 blk(256);
  // convert weights, then inputs: Ab = [bf16(z1); bf16(z2)]
  tobf16_2<<<512, blk, 0, stream>>>(lw1, lw2, W1b, 512 * 512 / 4);
  tobf16_2<<<4096, blk, 0, stream>>>(z1, z2, Ab, (int)(ND / 4));

  dim3 gg(4, 32, 2);  // 512/128, 4096/128, batch 2
  gemm_mfma<1><<<gg, blk, 0, stream>>>(Ab, W1b, lb1, la, Bb);     // prelu layer
  gemm_mfma<0><<<gg, blk, 0, stream>>>(Bb, W2b, lb2, la, Ab);     // second layer
  rownorm_bf16<<<2 * NN, blk, 0, stream>>>(Ab, Bb);               // -> na | nb

  sim_mfma<<<dim3(NN / 128, NN / 128), dim3(512), 0, stream>>>(Bb, Bb + ND,
                                                               mask, zbf);
  local_fin<<<NN / 256, blk, 0, stream>>>(zbf, scal);

  // global (DGI) part
  colmean<<<dim3(DD / 256, 64), blk, 0, stream>>>(z1, z2, s1, s2);
  matvec2<<<dim3(DD / 4, 2), blk, 0, stream>>>(gw1, s1, s2, gb1, ga, 1, t1, t2);
  matvec2<<<dim3(DD / 4, 2), blk, 0, stream>>>(gw2, t1, t2, gb2, nullptr, 0, hg1, hg2);
  matvec2<<<dim3(DD / 4, 2), blk, 0, stream>>>(W, hg1, hg2, nullptr, nullptr, 0, summ1, summ2);
  logsig2<<<dim3(NN / 4, 2), blk, 0, stream>>>(z1, z2, summ1, summ2, scal);

  combine<<<1, 1, 0, stream>>>(scal, out);
}